// Round 7
// baseline (410.742 us; speedup 1.0000x reference)
//
#include <hip/hip_runtime.h>
#include <hip/hip_bf16.h>
#include <math.h>

#define N_NODES 100000
#define N_EDGES 1600000
#define NHEADS 4
#define NEG_SLOPE 0.2f
// Coarse binning: 49 buckets of 2048 dst nodes, 8 sub-slabs each.
#define NBUK 49
#define BUKCAP 272       // LDS ring per bucket: 15 leftover + 256 burst max
#define SUBCAP 4608      // records per (bucket,sub): mean 4082 + 8 sigma
// D = H * D_hid = 128 channels for both layers

typedef __attribute__((ext_vector_type(8))) short short8;
typedef __attribute__((ext_vector_type(4))) float f32x4;

// float -> bf16 (round-to-nearest-even), values are finite here
__device__ __forceinline__ unsigned short f2bf(float f) {
    unsigned int u = __float_as_uint(f);
    u += 0x7fffu + ((u >> 16) & 1u);
    return (unsigned short)(u >> 16);
}
__device__ __forceinline__ float bf_lo(unsigned int u) {
    return __uint_as_float(u << 16);
}
__device__ __forceinline__ float bf_hi(unsigned int u) {
    return __uint_as_float(u & 0xffff0000u);
}
__device__ __forceinline__ short8 pack8(float4 f0, float4 f1) {
    short8 v;
    v[0] = (short)f2bf(f0.x); v[1] = (short)f2bf(f0.y);
    v[2] = (short)f2bf(f0.z); v[3] = (short)f2bf(f0.w);
    v[4] = (short)f2bf(f1.x); v[5] = (short)f2bf(f1.y);
    v[6] = (short)f2bf(f1.z); v[7] = (short)f2bf(f1.w);
    return v;
}

// ---------------------------------------------------------------------------
// Pack [W (128x128) | WA (128x8) pad to 16] into per-lane MFMA B-fragment
// order (bf16), 9 column-tiles. WA[k][c] = <W[k][hd*32..], a[hd]> computed
// inline (es/ed are linear in h, so the scores fold into the GEMM).
// ---------------------------------------------------------------------------
__global__ void pack_w_kernel(const float* __restrict__ W,
                              const float* __restrict__ a_src,
                              const float* __restrict__ a_dst,
                              unsigned short* __restrict__ Wp) {
    int idx = blockIdx.x * 256 + threadIdx.x;   // 0..18431
    if (idx >= 18432) return;
    int j    = idx & 7;
    int lane = (idx >> 3) & 63;
    int kc   = (idx >> 9) & 3;
    int ct   = idx >> 11;                        // 0..8
    int k = kc * 32 + ((lane >> 4) & 3) * 8 + j;
    int n = lane & 15;
    float v = 0.f;
    if (ct < 8) {
        v = W[k * 128 + ct * 16 + n];
    } else if (n < 8) {
        int hd = n & 3;
        const float* av = (n < 4 ? a_src : a_dst) + hd * 32;
        const float* wr = W + k * 128 + hd * 32;
#pragma unroll
        for (int t = 0; t < 32; ++t) v = fmaf(wr[t], av[t], v);
    }
    Wp[idx] = f2bf(v);
}

// ---------------------------------------------------------------------------
// MFMA GEMM + fused scores: [h | es ed] = x @ [W | WA].
// Block 256 thr = 4 waves; 128 rows/block (2 row-tiles of 16 per wave).
// K=128 as 4 chunks, 9 col-tiles of mfma_f32_16x16x32_bf16, fp32 accumulate.
// XF32: layer-1 reads fp32 features and converts inline.
// D layout: col=lane&15, row=quad*4+i. Scores go to compact split tables.
// ---------------------------------------------------------------------------
template <bool XF32>
__global__ __launch_bounds__(256) void gemm_mfma_kernel(
        const void* __restrict__ xv,
        const unsigned short* __restrict__ Wp,
        unsigned short* __restrict__ h,
        float* __restrict__ es, float* __restrict__ ed, int n_rows) {
    __shared__ unsigned short Wl[18432];   // 36 KB

    const int t = threadIdx.x;
    {
        const uint4* s4 = (const uint4*)Wp;
        uint4* d4 = (uint4*)Wl;
#pragma unroll
        for (int p = 0; p < 9; ++p) d4[p * 256 + t] = s4[p * 256 + t];
    }
    __syncthreads();

    const int lane = t & 63, wave = t >> 6;
    const int l15 = lane & 15, quad = lane >> 4;
    const int rbase = blockIdx.x * 128 + wave * 32;

    short8 a[2][4];
#pragma unroll
    for (int rt = 0; rt < 2; ++rt) {
        int r = rbase + rt * 16 + l15;
        r = r < n_rows ? r : n_rows - 1;         // clamp; stores are guarded
        if (XF32) {
            const float* xr = (const float*)xv + (size_t)r * 128 + quad * 8;
#pragma unroll
            for (int kc = 0; kc < 4; ++kc) {
                float4 f0 = *(const float4*)(xr + kc * 32);
                float4 f1 = *(const float4*)(xr + kc * 32 + 4);
                a[rt][kc] = pack8(f0, f1);
            }
        } else {
            const unsigned short* xr =
                (const unsigned short*)xv + (size_t)r * 128 + quad * 8;
#pragma unroll
            for (int kc = 0; kc < 4; ++kc)
                a[rt][kc] = *(const short8*)(xr + kc * 32);
        }
    }

    f32x4 acc[2][9];
#pragma unroll
    for (int rt = 0; rt < 2; ++rt)
#pragma unroll
        for (int ct = 0; ct < 9; ++ct)
            acc[rt][ct] = (f32x4){0.f, 0.f, 0.f, 0.f};

#pragma unroll
    for (int ct = 0; ct < 9; ++ct) {
#pragma unroll
        for (int kc = 0; kc < 4; ++kc) {
            short8 b = *(const short8*)&Wl[((ct * 4 + kc) * 64 + lane) * 8];
            acc[0][ct] = __builtin_amdgcn_mfma_f32_16x16x32_bf16(
                a[0][kc], b, acc[0][ct], 0, 0, 0);
            acc[1][ct] = __builtin_amdgcn_mfma_f32_16x16x32_bf16(
                a[1][kc], b, acc[1][ct], 0, 0, 0);
        }
    }

#pragma unroll
    for (int rt = 0; rt < 2; ++rt) {
#pragma unroll
        for (int i = 0; i < 4; ++i) {
            int r = rbase + rt * 16 + quad * 4 + i;
            if (r < n_rows) {
                unsigned short* hp = h + (size_t)r * 128 + l15;
#pragma unroll
                for (int ct = 0; ct < 8; ++ct)
                    hp[ct * 16] = f2bf(acc[rt][ct][i]);
                if (l15 < 4)      es[r * 4 + l15]       = acc[rt][8][i];
                else if (l15 < 8) ed[r * 4 + (l15 - 4)] = acc[rt][8][i];
            }
        }
    }
}

// ---------------------------------------------------------------------------
// CSR build. Level 1: LDS line-buffered binning -> every global write is a
// full 64B line assembled on ONE CU (fixes the 16x write amplification of
// per-record scatter). 49 buckets (dst>>11), 8 sub-slabs (blockIdx&7) to
// keep slab-position atomic chains shallow. Overflow-free: per iteration a
// bucket gets <=15 leftover + 256 burst < BUKCAP.
// Record = src | (dst&2047)<<17.
// ---------------------------------------------------------------------------
__global__ void zero_ints_kernel(int* __restrict__ p, int n) {
    int i = blockIdx.x * 256 + threadIdx.x;
    if (i < n) p[i] = 0;
}

__global__ __launch_bounds__(256) void bin_fill_kernel(
        const int* __restrict__ src, const int* __restrict__ dst,
        int* __restrict__ gcnt, unsigned int* __restrict__ slab) {
    __shared__ unsigned int lbuf[NBUK * BUKCAP];   // 53.3 KB
    __shared__ int cnt[NBUK];
    const int t = threadIdx.x;
    const int sub = blockIdx.x & 7;
    if (t < NBUK) cnt[t] = 0;
    __syncthreads();

    const int per = (N_EDGES + gridDim.x - 1) / gridDim.x;
    const int e0 = blockIdx.x * per;
    const int e1 = (e0 + per < N_EDGES) ? e0 + per : N_EDGES;

    for (int eb = e0; eb < e1; eb += 256) {
        int e = eb + t;
        if (e < e1) {
            int d = dst[e];
            int s = src[e];
            int bk = d >> 11;
            int pos = atomicAdd(&cnt[bk], 1);
            lbuf[bk * BUKCAP + pos] =
                (unsigned int)s | ((unsigned int)(d & 2047) << 17);
        }
        __syncthreads();
        if (t < NBUK) {
            int pending = cnt[t];
            int nl = pending >> 4;          // full 16-record lines
            if (nl > 0) {
                int gpos = atomicAdd(&gcnt[(t * 8 + sub) * 16], nl * 16);
                unsigned int* gp =
                    slab + (size_t)(t * 8 + sub) * SUBCAP + gpos;
                for (int l = 0; l < nl * 16; l += 4)
                    *(uint4*)(gp + l) = *(uint4*)&lbuf[t * BUKCAP + l];
                int rem = pending & 15;
                for (int r2 = 0; r2 < rem; ++r2)
                    lbuf[t * BUKCAP + r2] = lbuf[t * BUKCAP + nl * 16 + r2];
                cnt[t] = rem;
            }
        }
        __syncthreads();
    }
    // final partial-line flush (exact allocation; scalar stores, tiny)
    if (t < NBUK) {
        int rem = cnt[t];
        if (rem > 0) {
            int gpos = atomicAdd(&gcnt[(t * 8 + sub) * 16], rem);
            unsigned int* gp = slab + (size_t)(t * 8 + sub) * SUBCAP + gpos;
            for (int r2 = 0; r2 < rem; ++r2) gp[r2] = lbuf[t * BUKCAP + r2];
        }
    }
}

// Level 2a: per-bucket degree histogram (2048 LDS counters, coalesced deg out)
__global__ __launch_bounds__(256) void bin_hist_kernel(
        const int* __restrict__ gcnt, const unsigned int* __restrict__ slab,
        int* __restrict__ deg) {
    __shared__ int hist[2048];
    const int t = threadIdx.x;
    const int b = blockIdx.x;
    for (int i = t; i < 2048; i += 256) hist[i] = 0;
    __syncthreads();
    for (int sub = 0; sub < 8; ++sub) {
        int m = gcnt[(b * 8 + sub) * 16];
        const unsigned int* sp = slab + (size_t)(b * 8 + sub) * SUBCAP;
        for (int i = t; i < m; i += 256) atomicAdd(&hist[sp[i] >> 17], 1);
    }
    __syncthreads();
    for (int i = t; i < 2048; i += 256) {
        int node = b * 2048 + i;
        if (node < N_NODES) deg[node] = hist[i];
    }
}

__global__ __launch_bounds__(256) void scan1_kernel(const int* __restrict__ deg,
                                                    int* __restrict__ rowptr,
                                                    int* __restrict__ partials) {
    __shared__ int wsum[4];
    int i = blockIdx.x * 256 + threadIdx.x;
    int lane = threadIdx.x & 63, wave = threadIdx.x >> 6;
    int orig = (i < N_NODES) ? deg[i] : 0;
    int v = orig;
#pragma unroll
    for (int off = 1; off < 64; off <<= 1) {
        int t = __shfl_up(v, off);
        if (lane >= off) v += t;
    }
    if (lane == 63) wsum[wave] = v;
    __syncthreads();
    int woff = 0;
#pragma unroll
    for (int w = 0; w < 4; ++w) if (w < wave) woff += wsum[w];
    if (i < N_NODES) rowptr[i] = v - orig + woff;
    if (threadIdx.x == 0)
        partials[blockIdx.x] = wsum[0] + wsum[1] + wsum[2] + wsum[3];
}

__global__ __launch_bounds__(512) void scan2_kernel(int* __restrict__ partials,
                                                    int nb) {
    __shared__ int wsum[8];
    int i = threadIdx.x;
    int lane = i & 63, wave = i >> 6;
    int orig = (i < nb) ? partials[i] : 0;
    int v = orig;
#pragma unroll
    for (int off = 1; off < 64; off <<= 1) {
        int t = __shfl_up(v, off);
        if (lane >= off) v += t;
    }
    if (lane == 63) wsum[wave] = v;
    __syncthreads();
    int woff = 0;
#pragma unroll
    for (int w = 0; w < 8; ++w) if (w < wave) woff += wsum[w];
    if (i < nb) partials[i] = v - orig + woff;
}

__global__ void scan3_kernel(int* __restrict__ rowptr,
                             const int* __restrict__ partials) {
    int i = blockIdx.x * 256 + threadIdx.x;
    if (i < N_NODES) rowptr[i] += partials[blockIdx.x];
}

// Level 2b: scatter into CSR. All writes land in the bucket's contiguous
// ~131 KB rowptr window, L2-resident on this block's CU -> dense writeback.
__global__ __launch_bounds__(256) void bin_scatter_kernel(
        const int* __restrict__ gcnt, const unsigned int* __restrict__ slab,
        const int* __restrict__ rowptr, int* __restrict__ csr_src) {
    __shared__ int rp[2048];
    __shared__ int c2[2048];
    const int t = threadIdx.x;
    const int b = blockIdx.x;
    for (int i = t; i < 2048; i += 256) {
        int node = b * 2048 + i;
        rp[i] = node < N_NODES ? rowptr[node] : 0;
        c2[i] = 0;
    }
    __syncthreads();
    for (int sub = 0; sub < 8; ++sub) {
        int m = gcnt[(b * 8 + sub) * 16];
        const unsigned int* sp = slab + (size_t)(b * 8 + sub) * SUBCAP;
        for (int i = t; i < m; i += 256) {
            unsigned int rec = sp[i];
            int local = rec >> 17;
            int pos = rp[local] + atomicAdd(&c2[local], 1);
            csr_src[pos] = (int)(rec & 0x1FFFFu);
        }
    }
}

// ---------------------------------------------------------------------------
// Gather aggregation, one wave per dst node.
// Lane = (edge-slot eo in [0,4)) x (channel-group cl in [0,16), 8 ch each).
// All payloads/scores for up to 32 edges prefetched into registers BEFORE
// accumulating (~16 loads in flight/wave). Edge indices: one coalesced
// 64-wide load, shfl-distributed. Score loads deduplicated 4x (cl<4 lanes
// load, shfl-broadcast). Epilogue fused: RELU->bf16 or log_softmax->fp32.
// Softmax max-shift dropped: shift-invariant, logits are O(1) in fp32.
// ---------------------------------------------------------------------------
template <bool LOGSOFTMAX>
__global__ __launch_bounds__(256) void aggregate_kernel(
        const int* __restrict__ csr_src, const int* __restrict__ rowptr,
        const int* __restrict__ deg,
        const float* __restrict__ es, const float* __restrict__ ed,
        const unsigned short* __restrict__ hb, const float* __restrict__ b,
        void* __restrict__ out) {
    const int lane = threadIdx.x & 63;
    const int wave = threadIdx.x >> 6;
    const int n = blockIdx.x * 4 + wave;
    if (n >= N_NODES) return;
    const int eo = lane >> 4;          // edge slot
    const int cl = lane & 15;          // channel group: channels cl*8..cl*8+7
    const int c0 = cl * 8;
    const int hd = cl >> 2;
    const float edn = ed[n * 4 + hd];
    const int base = rowptr[n];
    const int dg = deg[n];

    float acc[8] = {0.f, 0.f, 0.f, 0.f, 0.f, 0.f, 0.f, 0.f};
    float wsum = 0.f;

    if (dg > 0) {
        const int myidx = csr_src[base + (lane < dg ? lane : dg - 1)];
        const int nit = (dg + 3) >> 2;
        const int nf = nit < 8 ? nit : 8;

        uint4 P[8];
        float E[8];
#pragma unroll
        for (int j = 0; j < 8; ++j) {
            if (j < nf) {
                int s = __shfl(myidx, 4 * j + eo);       // 4j+eo <= 31
                P[j] = *(const uint4*)(hb + (size_t)s * 128 + c0);
                E[j] = (cl < 4) ? es[s * 4 + cl] : 0.f;  // dedup loaders
            }
        }
#pragma unroll
        for (int j = 0; j < 8; ++j) {
            if (j < nf) {
                float e = __shfl(E[j], (lane & 48) | (cl >> 2));
                int o = 4 * j + eo;
                float sc = e + edn;
                sc = sc > 0.f ? sc : NEG_SLOPE * sc;
                float w = (o < dg) ? __expf(sc) : 0.f;
                acc[0] = fmaf(w, bf_lo(P[j].x), acc[0]);
                acc[1] = fmaf(w, bf_hi(P[j].x), acc[1]);
                acc[2] = fmaf(w, bf_lo(P[j].y), acc[2]);
                acc[3] = fmaf(w, bf_hi(P[j].y), acc[3]);
                acc[4] = fmaf(w, bf_lo(P[j].z), acc[4]);
                acc[5] = fmaf(w, bf_hi(P[j].z), acc[5]);
                acc[6] = fmaf(w, bf_lo(P[j].w), acc[6]);
                acc[7] = fmaf(w, bf_hi(P[j].w), acc[7]);
                wsum += w;
            }
        }
        // rare tail: deg > 32
        for (int j = 8; j < nit; ++j) {
            int o = 4 * j + eo;
            int s = (o < 64) ? __shfl(myidx, o)
                             : csr_src[base + (o < dg ? o : dg - 1)];
            uint4 p = *(const uint4*)(hb + (size_t)s * 128 + c0);
            float e = es[s * 4 + hd];
            float sc = e + edn;
            sc = sc > 0.f ? sc : NEG_SLOPE * sc;
            float w = (o < dg) ? __expf(sc) : 0.f;
            acc[0] = fmaf(w, bf_lo(p.x), acc[0]);
            acc[1] = fmaf(w, bf_hi(p.x), acc[1]);
            acc[2] = fmaf(w, bf_lo(p.y), acc[2]);
            acc[3] = fmaf(w, bf_hi(p.y), acc[3]);
            acc[4] = fmaf(w, bf_lo(p.z), acc[4]);
            acc[5] = fmaf(w, bf_hi(p.z), acc[5]);
            acc[6] = fmaf(w, bf_lo(p.w), acc[6]);
            acc[7] = fmaf(w, bf_hi(p.w), acc[7]);
            wsum += w;
        }
    }

    // reduce the 4 edge slots
#pragma unroll
    for (int j = 0; j < 8; ++j) {
        acc[j] += __shfl_xor(acc[j], 16);
        acc[j] += __shfl_xor(acc[j], 32);
    }
    wsum += __shfl_xor(wsum, 16);
    wsum += __shfl_xor(wsum, 32);

    float inv = wsum > 0.f ? 1.f / wsum : 0.f;
    float bl[8];
    *(float4*)&bl[0] = *(const float4*)(b + c0);
    *(float4*)&bl[4] = *(const float4*)(b + c0 + 4);
    float v[8];
#pragma unroll
    for (int j = 0; j < 8; ++j) v[j] = acc[j] * inv + bl[j];

    if (!LOGSOFTMAX) {
        if (lane < 16) {
            unsigned int pk[4];
#pragma unroll
            for (int j = 0; j < 4; ++j) {
                float r0 = v[2 * j]     > 0.f ? v[2 * j]     : 0.f;
                float r1 = v[2 * j + 1] > 0.f ? v[2 * j + 1] : 0.f;
                pk[j] = (unsigned int)f2bf(r0) | ((unsigned int)f2bf(r1) << 16);
            }
            *(uint4*)((unsigned short*)out + (size_t)n * 128 + c0) =
                make_uint4(pk[0], pk[1], pk[2], pk[3]);
        }
    } else {
        float m = v[0];
#pragma unroll
        for (int j = 1; j < 8; ++j) m = fmaxf(m, v[j]);
#pragma unroll
        for (int s = 1; s < 16; s <<= 1) m = fmaxf(m, __shfl_xor(m, s));
        float se = 0.f;
#pragma unroll
        for (int j = 0; j < 8; ++j) se += __expf(v[j] - m);
#pragma unroll
        for (int s = 1; s < 16; s <<= 1) se += __shfl_xor(se, s);
        float ls = m + logf(se);
        if (lane < 16) {
            float* o = (float*)out + (size_t)n * 128 + c0;
            *(float4*)o = make_float4(v[0] - ls, v[1] - ls, v[2] - ls, v[3] - ls);
            *(float4*)(o + 4) = make_float4(v[4] - ls, v[5] - ls, v[6] - ls, v[7] - ls);
        }
    }
}

// ---------------------------------------------------------------------------
extern "C" void kernel_launch(void* const* d_in, const int* in_sizes, int n_in,
                              void* d_out, int out_size, void* d_ws, size_t ws_size,
                              hipStream_t stream) {
    const int*   edge = (const int*)d_in[0];     // (2, E)
    const int*   src  = edge;
    const int*   dst  = edge + N_EDGES;
    const float* feat = (const float*)d_in[1];   // (N, 128)
    const float* W1   = (const float*)d_in[2];
    const float* a1s  = (const float*)d_in[3];
    const float* a1d  = (const float*)d_in[4];
    const float* b1   = (const float*)d_in[5];
    const float* W2   = (const float*)d_in[6];
    const float* a2s  = (const float*)d_in[7];
    const float* a2d  = (const float*)d_in[8];
    const float* b2   = (const float*)d_in[9];
    float* out = (float*)d_out;

    // Workspace: hb | x1b (bf16 N*128) | Wp1 | Wp2 (18432 bf16)
    //          | es | ed (N*4 f32) | deg | rowptr (N int) | partials (512)
    //          | gcnt (NBUK*8*16 int) | slab (NBUK*8*SUBCAP uint) | csr_src (E)
    unsigned short* hb  = (unsigned short*)d_ws;
    unsigned short* x1b = hb + (size_t)N_NODES * 128;
    unsigned short* Wp1 = x1b + (size_t)N_NODES * 128;
    unsigned short* Wp2 = Wp1 + 18432;
    float* es = (float*)(Wp2 + 18432);
    float* ed = es + (size_t)N_NODES * 4;
    int* deg      = (int*)(ed + (size_t)N_NODES * 4);
    int* rowptr   = deg + N_NODES;
    int* partials = rowptr + N_NODES;
    int* gcnt     = partials + 512;
    unsigned int* slab = (unsigned int*)(gcnt + NBUK * 8 * 16);
    int* csr_src  = (int*)(slab + (size_t)NBUK * 8 * SUBCAP);

    const int node_blk = (N_NODES + 255) / 256;          // 391
    const int gemm_blk = (N_NODES + 127) / 128;          // 782
    const int agg_blk  = (N_NODES + 3) / 4;              // 25000

    // ---- CSR build (shared by both layers) ----
    zero_ints_kernel<<<(NBUK * 8 * 16 + 255) / 256, 256, 0, stream>>>(gcnt, NBUK * 8 * 16);
    bin_fill_kernel<<<256, 256, 0, stream>>>(src, dst, gcnt, slab);
    bin_hist_kernel<<<NBUK, 256, 0, stream>>>(gcnt, slab, deg);
    scan1_kernel<<<node_blk, 256, 0, stream>>>(deg, rowptr, partials);
    scan2_kernel<<<1, 512, 0, stream>>>(partials, node_blk);
    scan3_kernel<<<node_blk, 256, 0, stream>>>(rowptr, partials);
    bin_scatter_kernel<<<NBUK, 256, 0, stream>>>(gcnt, slab, rowptr, csr_src);

    // ---- weight packing (scores folded in as a 9th column tile) ----
    pack_w_kernel<<<72, 256, 0, stream>>>(W1, a1s, a1d, Wp1);
    pack_w_kernel<<<72, 256, 0, stream>>>(W2, a2s, a2d, Wp2);

    // ---- Layer 1 ----
    gemm_mfma_kernel<true><<<gemm_blk, 256, 0, stream>>>(feat, Wp1, hb, es, ed, N_NODES);
    aggregate_kernel<false><<<agg_blk, 256, 0, stream>>>(
        csr_src, rowptr, deg, es, ed, hb, b1, x1b);

    // ---- Layer 2 ----
    gemm_mfma_kernel<false><<<gemm_blk, 256, 0, stream>>>(x1b, Wp2, hb, es, ed, N_NODES);
    aggregate_kernel<true><<<agg_blk, 256, 0, stream>>>(
        csr_src, rowptr, deg, es, ed, hb, b2, out);
}